// Round 14
// baseline (706.085 us; speedup 1.0000x reference)
//
#include <hip/hip_runtime.h>
#include <hip/hip_bf16.h>

#define PCHUNK 2048
#define BSZ 128       // nodes per bucket
#define CAP 2560      // per-bucket edge capacity (mean 2046, +11 sigma)

__device__ inline float bf2f(unsigned int u16) { return __uint_as_float(u16 << 16); }
__device__ inline unsigned short f2bf(float f) {
    __hip_bfloat16 b = __float2bfloat16(f);
    return *(unsigned short*)&b;
}

typedef __attribute__((ext_vector_type(8))) short v8s;
typedef __attribute__((ext_vector_type(4))) float v4f;

// ---- fused graph build. grid = max(nchunks, nbkt) = 782 blocks, ALL co-resident
//      (37 KB LDS + launch_bounds(256,4) -> 4 blocks/CU x 256 CU = 1024 slots).
//      Zero global atomics: reservation replaced by hist-matrix + column scans. ----
__global__ void __launch_bounds__(256, 4)
k_build(const int* __restrict__ src, const int* __restrict__ dst, int E,
        int nchunks, int nbkt, int* __restrict__ bar,
        int* __restrict__ hist_g, int* __restrict__ colscan_g,
        unsigned int* __restrict__ buckets,
        int* __restrict__ offs, int* __restrict__ deg, float* __restrict__ dinv,
        int* __restrict__ csr,
        const float* __restrict__ x, const float* __restrict__ W1,
        unsigned short* __restrict__ A, int N,
        float* __restrict__ zero_base, int zero_count) {
    __shared__ int hist[1024];
    __shared__ int excl[1024];
    __shared__ int cursor[1024];          // reused as column counts in 1b
    __shared__ unsigned int staged_e[PCHUNK];
    __shared__ unsigned short staged_b[PCHUNK];
    __shared__ int wtot[4];
    __shared__ int cnt_s;
    __shared__ int dl[BSZ], cur2[BSZ];
    __shared__ float dis[BSZ];
    __shared__ float xs[BSZ * 6];
    __shared__ float W1s[6 * 64];
    __shared__ int w0tot;

    int t = threadIdx.x, lane = t & 63, wave = t >> 6;
    int B = blockIdx.x;

    // zero pool region (consumed much later by pull_pool)
    for (int i = B * 256 + t; i < zero_count; i += gridDim.x * 256)
        zero_base[i] = 0.f;

    // ================= 1a: chunk role — hist + bucket-sort in LDS =============
    int nE = 0;
    if (B < nchunks) {
        int base = B * PCHUNK;
        nE = E - base; if (nE > PCHUNK) nE = PCHUNK; if (nE < 0) nE = 0;
        for (int i = t; i < 1024; i += 256) hist[i] = 0;
        __syncthreads();
        int dreg[8];
        #pragma unroll
        for (int j = 0; j < 8; ++j) {
            int ii = t + j * 256;
            dreg[j] = (ii < nE) ? dst[base + ii] : -1;
        }
        #pragma unroll
        for (int j = 0; j < 8; ++j)
            if (dreg[j] >= 0) atomicAdd(&hist[dreg[j] >> 7], 1);
        __syncthreads();
        for (int b = t; b < nbkt; b += 256) hist_g[(size_t)B * nbkt + b] = hist[b];
        // exclusive scan over 1024 (4 per thread + wave shfl)
        int h0 = hist[4*t], h1 = hist[4*t+1], h2 = hist[4*t+2], h3 = hist[4*t+3];
        int p1 = h0 + h1, p2 = p1 + h2, s = p2 + h3;
        int si = s;
        #pragma unroll
        for (int off = 1; off < 64; off <<= 1) {
            int u = __shfl_up(si, off, 64);
            if (lane >= off) si += u;
        }
        if (lane == 63) wtot[wave] = si;
        __syncthreads();
        int woff = 0;
        #pragma unroll
        for (int w2 = 0; w2 < 4; ++w2) woff += (w2 < wave) ? wtot[w2] : 0;
        int eb = woff + si - s;
        excl[4*t] = eb;       cursor[4*t] = eb;
        excl[4*t+1] = eb+h0;  cursor[4*t+1] = eb+h0;
        excl[4*t+2] = eb+p1;  cursor[4*t+2] = eb+p1;
        excl[4*t+3] = eb+p2;  cursor[4*t+3] = eb+p2;
        __syncthreads();
        #pragma unroll
        for (int j = 0; j < 8; ++j) {
            if (dreg[j] >= 0) {
                int e = base + t + j * 256;
                int d = dreg[j];
                int b = d >> 7;
                int r = atomicAdd(&cursor[b], 1);
                staged_e[r] = (unsigned int)src[e] | ((unsigned int)(d & (BSZ - 1)) << 24);
                staged_b[r] = (unsigned short)b;
            }
        }
    }
    // ---- device barrier 0 ----
    __threadfence(); __syncthreads();
    if (t == 0) { atomicAdd(&bar[0], 1); while (atomicAdd(&bar[0], 0) < (int)gridDim.x) {} }
    __syncthreads(); __threadfence();

    // ================= 1b: bucket role — column scan -> colscan row ===========
    if (B < nbkt) {
        for (int c = t; c < 1024; c += 256)
            cursor[c] = (c < nchunks) ? hist_g[(size_t)c * nbkt + B] : 0;
        __syncthreads();
        int h0 = cursor[4*t], h1 = cursor[4*t+1], h2 = cursor[4*t+2], h3 = cursor[4*t+3];
        int p1 = h0 + h1, p2 = p1 + h2, s = p2 + h3;
        int si = s;
        #pragma unroll
        for (int off = 1; off < 64; off <<= 1) {
            int u = __shfl_up(si, off, 64);
            if (lane >= off) si += u;
        }
        if (lane == 63) wtot[wave] = si;
        __syncthreads();
        int woff = 0;
        #pragma unroll
        for (int w2 = 0; w2 < 4; ++w2) woff += (w2 < wave) ? wtot[w2] : 0;
        int eb = woff + si - s;
        int ex4[4] = {eb, eb + h0, eb + p1, eb + p2};
        #pragma unroll
        for (int j = 0; j < 4; ++j) {
            int c = 4 * t + j;
            if (c < nchunks) colscan_g[(size_t)B * nchunks + c] = ex4[j];
        }
        if (t == 0) cnt_s = wtot[0] + wtot[1] + wtot[2] + wtot[3];
    }
    // ---- device barrier 1 ----
    __threadfence(); __syncthreads();
    if (t == 0) { atomicAdd(&bar[16], 1); while (atomicAdd(&bar[16], 0) < (int)gridDim.x) {} }
    __syncthreads(); __threadfence();

    // ================= 1c: chunk role — scatter staged edges compactly ========
    if (B < nchunks) {
        for (int i = t; i < nE; i += 256) {
            int b = staged_b[i];
            int off = colscan_g[(size_t)b * nchunks + B];
            int local = off + (i - excl[b]);
            if (local < CAP) buckets[(size_t)b * CAP + local] = staged_e[i];
        }
    }
    // ---- device barrier 2 ----
    __threadfence(); __syncthreads();
    if (t == 0) { atomicAdd(&bar[32], 1); while (atomicAdd(&bar[32], 0) < (int)gridDim.x) {} }
    __syncthreads(); __threadfence();

    // ================= 2: bucket role — CSR build + fused xw1 =================
    if (B < nbkt) {
        int nb0 = B * BSZ;
        for (int i = t; i < 6 * 64; i += 256) W1s[i] = W1[i];
        for (int i = t; i < BSZ * 6; i += 256) {
            int node = nb0 + i / 6;
            xs[i] = (node < N) ? x[(size_t)nb0 * 6 + i] : 0.f;
        }
        if (t < BSZ) dl[t] = 0;
        __syncthreads();
        int cnt = cnt_s;
        if (cnt > CAP) cnt = CAP;
        const unsigned int* bp = buckets + (size_t)B * CAP;
        for (int i = t; i < cnt; i += 256) atomicAdd(&dl[bp[i] >> 24], 1);
        __syncthreads();
        int v = (t < BSZ) ? dl[t] : 0;
        int si = v;
        #pragma unroll
        for (int off = 1; off < 64; off <<= 1) {
            int u = __shfl_up(si, off, 64);
            if (lane >= off) si += u;
        }
        if (t == 63) w0tot = si;
        __syncthreads();
        int ex = si - v + ((wave == 1) ? w0tot : 0);
        if (t < BSZ) {
            cur2[t] = ex;
            float di = rsqrtf((float)v + 1.0f);
            dis[t] = di;
            int n = nb0 + t;
            if (n < N) { offs[n] = B * CAP + ex; deg[n] = v; dinv[n] = di; }
        }
        __syncthreads();
        int* cg = csr + (size_t)B * CAP;
        for (int i = t; i < cnt; i += 256) {
            unsigned int e = bp[i];
            int r = atomicAdd(&cur2[e >> 24], 1);
            cg[r] = (int)(e & 0x00FFFFFFu);
        }
        int ch = t & 63, sub = t >> 6;
        for (int nl = sub; nl < BSZ; nl += 4) {
            int node = nb0 + nl;
            if (node < N) {
                float acc = 0.f;
                #pragma unroll
                for (int k = 0; k < 6; ++k) acc += xs[nl * 6 + k] * W1s[k * 64 + ch];
                A[(size_t)node * 64 + ch] = f2bf(acc * dis[nl]);
            }
        }
    }
}

// ---- pull conv1 + fused xw2 MFMA (4 ch/lane, R12-proven) ----
__global__ void k_pull1_xw2(const unsigned short* __restrict__ A, const int* __restrict__ csr,
                            const int* __restrict__ offs, const int* __restrict__ deg,
                            const float* __restrict__ dinv, const float* __restrict__ bias,
                            const float* __restrict__ W2, unsigned short* __restrict__ A2,
                            int N) {
    __shared__ unsigned short Ht[16][72];
    int t = threadIdx.x;
    int lane = t & 63, wave = t >> 6;
    int q = lane >> 4, m = lane & 15;
    int cbase = wave * 16;
    v8s b0h, b0l, b1h, b1l;
    #pragma unroll
    for (int j = 0; j < 8; ++j) {
        float w0 = W2[(q * 8 + j) * 64 + cbase + m];
        unsigned short h0 = f2bf(w0);
        b0h[j] = (short)h0;
        b0l[j] = (short)f2bf(w0 - bf2f(h0));
        float w1 = W2[(32 + q * 8 + j) * 64 + cbase + m];
        unsigned short h1 = f2bf(w1);
        b1h[j] = (short)h1;
        b1l[j] = (short)f2bf(w1 - bf2f(h1));
    }
    int n0 = blockIdx.x * 16;
    int nl = wave * 4 + q;
    int n = n0 + nl;
    bool valid = n < N;
    int nc = valid ? n : N - 1;
    int base = offs[nc];
    int dg = valid ? deg[nc] : 0;
    int dgm = dg, o;
    o = __shfl_xor(dgm, 16, 64); dgm = dgm > o ? dgm : o;
    o = __shfl_xor(dgm, 32, 64); dgm = dgm > o ? dgm : o;
    uint2 su = *(const uint2*)(A + ((size_t)nc << 6) + 4 * m);
    float a0 = __uint_as_float(su.x << 16);
    float a1 = __uint_as_float(su.x & 0xffff0000u);
    float a2 = __uint_as_float(su.y << 16);
    float a3 = __uint_as_float(su.y & 0xffff0000u);
    int i = 0;
    for (; i + 8 <= dgm; i += 8) {
        uint2 u[8];
        #pragma unroll
        for (int j = 0; j < 8; ++j) {
            unsigned int s = (unsigned int)csr[base + i + j];
            if (s >= (unsigned int)N) s = 0;
            u[j] = *(const uint2*)(A + ((size_t)s << 6) + 4 * m);
        }
        #pragma unroll
        for (int j = 0; j < 8; ++j) {
            unsigned int ux = (i + j < dg) ? u[j].x : 0u;
            unsigned int uy = (i + j < dg) ? u[j].y : 0u;
            a0 += __uint_as_float(ux << 16);
            a1 += __uint_as_float(ux & 0xffff0000u);
            a2 += __uint_as_float(uy << 16);
            a3 += __uint_as_float(uy & 0xffff0000u);
        }
    }
    for (; i < dgm; ++i) {
        unsigned int s = (unsigned int)csr[base + i];
        if (s >= (unsigned int)N) s = 0;
        uint2 uu = *(const uint2*)(A + ((size_t)s << 6) + 4 * m);
        unsigned int ux = (i < dg) ? uu.x : 0u;
        unsigned int uy = (i < dg) ? uu.y : 0u;
        a0 += __uint_as_float(ux << 16);
        a1 += __uint_as_float(ux & 0xffff0000u);
        a2 += __uint_as_float(uy << 16);
        a3 += __uint_as_float(uy & 0xffff0000u);
    }
    float di = valid ? dinv[n] : 0.f;
    float4 bb = *(const float4*)(bias + 4 * m);
    float v0 = fmaxf(fmaf(di, a0, bb.x), 0.f);
    float v1 = fmaxf(fmaf(di, a1, bb.y), 0.f);
    float v2 = fmaxf(fmaf(di, a2, bb.z), 0.f);
    float v3 = fmaxf(fmaf(di, a3, bb.w), 0.f);
    if (valid) {
        uint2 pk;
        pk.x = (unsigned int)f2bf(v0) | ((unsigned int)f2bf(v1) << 16);
        pk.y = (unsigned int)f2bf(v2) | ((unsigned int)f2bf(v3) << 16);
        *(uint2*)&Ht[nl][4 * m] = pk;
    }
    __syncthreads();
    union { uint4 u; v8s s; } a0u, a1u;
    a0u.u = *(const uint4*)&Ht[m][q * 8];
    a1u.u = *(const uint4*)&Ht[m][32 + q * 8];
    v4f acc = {0.f, 0.f, 0.f, 0.f};
    acc = __builtin_amdgcn_mfma_f32_16x16x32_bf16(a0u.s, b0l, acc, 0, 0, 0);
    acc = __builtin_amdgcn_mfma_f32_16x16x32_bf16(a1u.s, b1l, acc, 0, 0, 0);
    acc = __builtin_amdgcn_mfma_f32_16x16x32_bf16(a0u.s, b0h, acc, 0, 0, 0);
    acc = __builtin_amdgcn_mfma_f32_16x16x32_bf16(a1u.s, b1h, acc, 0, 0, 0);
    #pragma unroll
    for (int r = 0; r < 4; ++r) {
        int node = n0 + q * 4 + r;
        if (node < N)
            A2[(size_t)node * 64 + cbase + m] = f2bf(acc[r] * dinv[node]);
    }
}

// ---- pull conv2 + mean-pool (4 ch/lane, LDS-transposed contiguous atomics, R12-proven) ----
__global__ void k_pull_pool(const unsigned short* __restrict__ A, const int* __restrict__ csr,
                            const int* __restrict__ offs, const int* __restrict__ deg,
                            const float* __restrict__ dinv, const float* __restrict__ bias,
                            const int* __restrict__ batch, float* __restrict__ pool, int N) {
    __shared__ float vt[4][4][64];
    int t = threadIdx.x;
    int lane = t & 63, wave = t >> 6;
    int q = lane >> 4, m = lane & 15;
    int n0 = blockIdx.x * 16;
    int nl = wave * 4 + q;
    int n = n0 + nl;
    bool valid = n < N;
    int nc = valid ? n : N - 1;
    int base = offs[nc];
    int dg = valid ? deg[nc] : 0;
    int dgm = dg, o;
    o = __shfl_xor(dgm, 16, 64); dgm = dgm > o ? dgm : o;
    o = __shfl_xor(dgm, 32, 64); dgm = dgm > o ? dgm : o;
    uint2 su = *(const uint2*)(A + ((size_t)nc << 6) + 4 * m);
    float a0 = __uint_as_float(su.x << 16);
    float a1 = __uint_as_float(su.x & 0xffff0000u);
    float a2 = __uint_as_float(su.y << 16);
    float a3 = __uint_as_float(su.y & 0xffff0000u);
    int i = 0;
    for (; i + 8 <= dgm; i += 8) {
        uint2 u[8];
        #pragma unroll
        for (int j = 0; j < 8; ++j) {
            unsigned int s = (unsigned int)csr[base + i + j];
            if (s >= (unsigned int)N) s = 0;
            u[j] = *(const uint2*)(A + ((size_t)s << 6) + 4 * m);
        }
        #pragma unroll
        for (int j = 0; j < 8; ++j) {
            unsigned int ux = (i + j < dg) ? u[j].x : 0u;
            unsigned int uy = (i + j < dg) ? u[j].y : 0u;
            a0 += __uint_as_float(ux << 16);
            a1 += __uint_as_float(ux & 0xffff0000u);
            a2 += __uint_as_float(uy << 16);
            a3 += __uint_as_float(uy & 0xffff0000u);
        }
    }
    for (; i < dgm; ++i) {
        unsigned int s = (unsigned int)csr[base + i];
        if (s >= (unsigned int)N) s = 0;
        uint2 uu = *(const uint2*)(A + ((size_t)s << 6) + 4 * m);
        unsigned int ux = (i < dg) ? uu.x : 0u;
        unsigned int uy = (i < dg) ? uu.y : 0u;
        a0 += __uint_as_float(ux << 16);
        a1 += __uint_as_float(ux & 0xffff0000u);
        a2 += __uint_as_float(uy << 16);
        a3 += __uint_as_float(uy & 0xffff0000u);
    }
    float di = valid ? dinv[n] : 0.f;
    float4 bb = *(const float4*)(bias + 4 * m);
    float4 vv;
    vv.x = fmaxf(fmaf(di, a0, bb.x), 0.f);
    vv.y = fmaxf(fmaf(di, a1, bb.y), 0.f);
    vv.z = fmaxf(fmaf(di, a2, bb.z), 0.f);
    vv.w = fmaxf(fmaf(di, a3, bb.w), 0.f);
    *(float4*)&vt[wave][q][4 * m] = vv;
    __syncthreads();
    int nw0 = n0 + wave * 4;
    #pragma unroll
    for (int r = 0; r < 4; ++r) {
        int nn = nw0 + r;
        if (nn < N) {
            float v = vt[wave][r][lane];
            atomicAdd(&pool[(size_t)batch[nn] * 64 + lane], v);
        }
    }
}

// per-graph head, 4 graphs per block; lin1W staged in LDS
__global__ void k_final4(const float* __restrict__ pool, const int* __restrict__ batch,
                         int N, int G,
                         const int* __restrict__ lig, const int* __restrict__ add,
                         const int* __restrict__ base, const int* __restrict__ aryl,
                         const float* __restrict__ e_lig, const float* __restrict__ e_add,
                         const float* __restrict__ e_base, const float* __restrict__ e_aryl,
                         const float* __restrict__ lin1W, const float* __restrict__ lin1b,
                         const float* __restrict__ lin2W, const float* __restrict__ lin2b,
                         float* __restrict__ out) {
    __shared__ float Wl[128 * 64];
    __shared__ float cat[4][128];
    int t = threadIdx.x;
    int c = t & 63, wv = t >> 6;
    for (int i = t; i < 128 * 64; i += 256) Wl[i] = lin1W[i];
    int g = blockIdx.x * 4 + wv;
    if (g < G) {
        int res = 0;
        if (c < 2) {
            int target = g + c;
            int lo = 0, hi = N;
            while (lo < hi) {
                int mid = (lo + hi) >> 1;
                if (batch[mid] < target) lo = mid + 1; else hi = mid;
            }
            res = lo;
        }
        int lo = __shfl(res, 0, 64), hi = __shfl(res, 1, 64);
        float invc = 1.0f / fmaxf((float)(hi - lo), 1.0f);
        cat[wv][c] = pool[(size_t)g * 64 + c] * invc;
        float ev;
        if (c < 16)      ev = e_lig[lig[g] * 16 + c];
        else if (c < 32) ev = e_add[add[g] * 16 + (c - 16)];
        else if (c < 48) ev = e_base[base[g] * 16 + (c - 32)];
        else             ev = e_aryl[aryl[g] * 16 + (c - 48)];
        cat[wv][64 + c] = ev;
    }
    __syncthreads();
    if (g < G) {
        float acc = lin1b[c];
        #pragma unroll
        for (int k = 0; k < 128; ++k) acc += cat[wv][k] * Wl[k * 64 + c];
        float p = fmaxf(acc, 0.f) * lin2W[c];
        #pragma unroll
        for (int off = 32; off > 0; off >>= 1) p += __shfl_down(p, off, 64);
        if (c == 0) out[g] = p + lin2b[0];
    }
}

extern "C" void kernel_launch(void* const* d_in, const int* in_sizes, int n_in,
                              void* d_out, int out_size, void* d_ws, size_t ws_size,
                              hipStream_t stream) {
    const float* x      = (const float*)d_in[0];
    const int*   ei     = (const int*)d_in[1];
    const int*   batch  = (const int*)d_in[2];
    const int*   lig    = (const int*)d_in[3];
    const int*   addi   = (const int*)d_in[4];
    const int*   basei  = (const int*)d_in[5];
    const int*   aryl   = (const int*)d_in[6];
    const float* e_lig  = (const float*)d_in[7];
    const float* e_add  = (const float*)d_in[8];
    const float* e_base = (const float*)d_in[9];
    const float* e_aryl = (const float*)d_in[10];
    const float* W1     = (const float*)d_in[11];
    const float* b1     = (const float*)d_in[12];
    const float* W2     = (const float*)d_in[13];
    const float* b2     = (const float*)d_in[14];
    const float* lin1W  = (const float*)d_in[15];
    const float* lin1b  = (const float*)d_in[16];
    const float* lin2W  = (const float*)d_in[17];
    const float* lin2b  = (const float*)d_in[18];
    float* out = (float*)d_out;

    const int N = in_sizes[0] / 6;
    const int E = in_sizes[1] / 2;
    const int G = in_sizes[3];
    const int* src = ei;
    const int* dst = ei + E;
    const int nbkt = (N + BSZ - 1) / BSZ;            // 782 buckets
    const int nchunks = (E + PCHUNK - 1) / PCHUNK;   // 782 chunks
    const int nblk = nchunks > nbkt ? nchunks : nbkt;

    // ---- workspace layout ----
    char* w = (char*)d_ws;
    size_t SA = (size_t)N * 64;
    unsigned short* A  = (unsigned short*)w;  w += SA * 2;  // Abar conv1 (bf16)
    unsigned short* A2 = (unsigned short*)w;  w += SA * 2;  // Abar conv2 (bf16)
    float* dinv = (float*)w;   w += (size_t)N * 4;
    int*   deg  = (int*)w;     w += (size_t)N * 4;
    int*   offs = (int*)w;     w += (size_t)N * 4;
    float* pool = (float*)w;   w += (size_t)G * 64 * 4;     // zeroed by k_build
    int*   bar  = (int*)w;     w += 192;                    // zeroed by memset
    int* hist_g = (int*)w;     w += (size_t)nchunks * nbkt * 4;
    int* colscan_g = (int*)w;  w += (size_t)nbkt * nchunks * 4;
    unsigned int* buckets = (unsigned int*)w;  w += (size_t)nbkt * CAP * 4;
    int* csr    = (int*)w;     w += (size_t)nbkt * CAP * 4;
    w += 4096;   // slack: packed pulls read up to dgm past a node's csr end

    hipMemsetAsync(bar, 0, 192, stream);

    // fused graph build (partition + CSR + xw1), all blocks co-resident
    k_build<<<nblk, 256, 0, stream>>>(src, dst, E, nchunks, nbkt, bar,
                                      hist_g, colscan_g, buckets,
                                      offs, deg, dinv, csr, x, W1, A, N,
                                      pool, G * 64);

    // conv1 pull (4ch/lane) + fused xw2 MFMA
    k_pull1_xw2<<<(N + 15) / 16, 256, 0, stream>>>(A, csr, offs, deg, dinv, b1, W2, A2, N);

    // conv2 + fused pooling (4ch/lane, LDS-transposed contiguous atomics)
    k_pull_pool<<<(N + 15) / 16, 256, 0, stream>>>(A2, csr, offs, deg, dinv, b2, batch, pool, N);

    // head (4 graphs per block)
    k_final4<<<(G + 3) / 4, 256, 0, stream>>>(pool, batch, N, G, lig, addi, basei, aryl,
                                              e_lig, e_add, e_base, e_aryl,
                                              lin1W, lin1b, lin2W, lin2b, out);
}

// Round 15
// 246.794 us; speedup vs baseline: 2.8610x; 2.8610x over previous
//
#include <hip/hip_runtime.h>
#include <hip/hip_bf16.h>

#define PCHUNK 4096
#define NBK 1024      // hist width (padded); used buckets = ceil(100000/128) = 782
#define BSZ 128       // nodes per bucket
#define CAP 2560      // per-bucket edge capacity (mean 2046, +11 sigma)
#define CNT_STRIDE 16 // bucket_cnt padded: one 64B cacheline per bucket

__device__ inline float bf2f(unsigned int u16) { return __uint_as_float(u16 << 16); }
__device__ inline unsigned short f2bf(float f) {
    __hip_bfloat16 b = __float2bfloat16(f);
    return *(unsigned short*)&b;
}

typedef __attribute__((ext_vector_type(8))) short v8s;
typedef __attribute__((ext_vector_type(4))) float v4f;

// ---- phase 1: partition edges into 128-node dst-buckets; also zeroes pool.
//      bucket_cnt padded 1 line/bucket -> reservation atomics serialize 391-deep
//      per line instead of 6.2k-deep (R12's hidden cost). ----
__global__ void k_partition(const int* __restrict__ src, const int* __restrict__ dst, int E,
                            int* __restrict__ bucket_cnt, unsigned int* __restrict__ buckets,
                            float* __restrict__ zero_base, int zero_count) {
    __shared__ int hist[NBK];
    __shared__ int shift[NBK];
    __shared__ int cursor[NBK];
    __shared__ unsigned int staged_e[PCHUNK];
    __shared__ unsigned short staged_b[PCHUNK];
    __shared__ int wtot[4];
    int t = threadIdx.x;
    int lane = t & 63, wave = t >> 6;
    int base = blockIdx.x * PCHUNK;
    for (int i = blockIdx.x * 256 + t; i < zero_count; i += gridDim.x * 256)
        zero_base[i] = 0.f;
    for (int i = t; i < NBK; i += 256) hist[i] = 0;
    __syncthreads();
    int nE = E - base; if (nE > PCHUNK) nE = PCHUNK;
    for (int i = t; i < nE; i += 256) atomicAdd(&hist[dst[base + i] >> 7], 1);
    __syncthreads();
    int h0 = hist[4 * t], h1 = hist[4 * t + 1], h2 = hist[4 * t + 2], h3 = hist[4 * t + 3];
    int p1 = h0 + h1, p2 = p1 + h2, s = p2 + h3;
    int si = s;
    #pragma unroll
    for (int off = 1; off < 64; off <<= 1) {
        int u = __shfl_up(si, off, 64);
        if (lane >= off) si += u;
    }
    if (lane == 63) wtot[wave] = si;
    __syncthreads();
    int woff = 0;
    #pragma unroll
    for (int w2 = 0; w2 < 4; ++w2) woff += (w2 < wave) ? wtot[w2] : 0;
    int ebase = woff + si - s;
    int ex[4] = {ebase, ebase + h0, ebase + p1, ebase + p2};
    int cn[4] = {h0, h1, h2, h3};
    #pragma unroll
    for (int j = 0; j < 4; ++j) {
        int bidx = 4 * t + j;
        cursor[bidx] = ex[j];
        if (cn[j] > 0) {
            int g = atomicAdd(&bucket_cnt[bidx * CNT_STRIDE], cn[j]);
            shift[bidx] = g - ex[j];
        }
    }
    __syncthreads();
    for (int i = t; i < nE; i += 256) {
        int d = dst[base + i];
        int b = d >> 7;
        int r = atomicAdd(&cursor[b], 1);
        staged_e[r] = (unsigned int)src[base + i] | ((unsigned int)(d & (BSZ - 1)) << 24);
        staged_b[r] = (unsigned short)b;
    }
    __syncthreads();
    for (int i = t; i < nE; i += 256) {
        int b = staged_b[i];
        buckets[(size_t)b * CAP + shift[b] + i] = staged_e[i];
    }
}

// ---- phase 2: per-bucket CSR build + fused xw1 (R9-proven) ----
__global__ void k_bucket_csr_xw1(const unsigned int* __restrict__ buckets,
                                 const int* __restrict__ bucket_cnt,
                                 int* __restrict__ offs, int* __restrict__ deg,
                                 float* __restrict__ dinv, int* __restrict__ csr,
                                 const float* __restrict__ x, const float* __restrict__ W1,
                                 unsigned short* __restrict__ A, int N) {
    __shared__ int dl[BSZ], cur[BSZ];
    __shared__ float dis[BSZ];
    __shared__ float W1s[6 * 64];
    __shared__ float xs[BSZ * 6];
    __shared__ int w0tot;
    int b = blockIdx.x, t = threadIdx.x;
    int nb0 = b * BSZ;
    for (int i = t; i < 6 * 64; i += 256) W1s[i] = W1[i];
    for (int i = t; i < BSZ * 6; i += 256) {
        int node = nb0 + i / 6;
        xs[i] = (node < N) ? x[(size_t)nb0 * 6 + i] : 0.f;
    }
    if (t < BSZ) dl[t] = 0;
    __syncthreads();
    int cnt = bucket_cnt[b * CNT_STRIDE];
    if (cnt > CAP) cnt = CAP;
    const unsigned int* bp = buckets + (size_t)b * CAP;
    for (int i = t; i < cnt; i += 256) atomicAdd(&dl[bp[i] >> 24], 1);
    __syncthreads();
    int lane = t & 63, wave = t >> 6;
    int v = (t < BSZ) ? dl[t] : 0;
    int si = v;
    #pragma unroll
    for (int off = 1; off < 64; off <<= 1) {
        int u = __shfl_up(si, off, 64);
        if (lane >= off) si += u;
    }
    if (t == 63) w0tot = si;
    __syncthreads();
    int ex = si - v + ((wave == 1) ? w0tot : 0);
    if (t < BSZ) {
        cur[t] = ex;
        float di = rsqrtf((float)v + 1.0f);
        dis[t] = di;
        int n = nb0 + t;
        if (n < N) { offs[n] = b * CAP + ex; deg[n] = v; dinv[n] = di; }
    }
    __syncthreads();
    int* cg = csr + (size_t)b * CAP;
    for (int i = t; i < cnt; i += 256) {
        unsigned int e = bp[i];
        int r = atomicAdd(&cur[e >> 24], 1);
        cg[r] = (int)(e & 0x00FFFFFFu);
    }
    int ch = t & 63, sub = t >> 6;
    for (int nl = sub; nl < BSZ; nl += 4) {
        int node = nb0 + nl;
        if (node < N) {
            float acc = 0.f;
            #pragma unroll
            for (int k = 0; k < 6; ++k) acc += xs[nl * 6 + k] * W1s[k * 64 + ch];
            A[(size_t)node * 64 + ch] = f2bf(acc * dis[nl]);
        }
    }
}

// ---- pull conv1 + fused xw2 MFMA (4 ch/lane, R12-proven) ----
__global__ void k_pull1_xw2(const unsigned short* __restrict__ A, const int* __restrict__ csr,
                            const int* __restrict__ offs, const int* __restrict__ deg,
                            const float* __restrict__ dinv, const float* __restrict__ bias,
                            const float* __restrict__ W2, unsigned short* __restrict__ A2,
                            int N) {
    __shared__ unsigned short Ht[16][72];
    int t = threadIdx.x;
    int lane = t & 63, wave = t >> 6;
    int q = lane >> 4, m = lane & 15;
    int cbase = wave * 16;
    v8s b0h, b0l, b1h, b1l;
    #pragma unroll
    for (int j = 0; j < 8; ++j) {
        float w0 = W2[(q * 8 + j) * 64 + cbase + m];
        unsigned short h0 = f2bf(w0);
        b0h[j] = (short)h0;
        b0l[j] = (short)f2bf(w0 - bf2f(h0));
        float w1 = W2[(32 + q * 8 + j) * 64 + cbase + m];
        unsigned short h1 = f2bf(w1);
        b1h[j] = (short)h1;
        b1l[j] = (short)f2bf(w1 - bf2f(h1));
    }
    int n0 = blockIdx.x * 16;
    int nl = wave * 4 + q;
    int n = n0 + nl;
    bool valid = n < N;
    int nc = valid ? n : N - 1;
    int base = offs[nc];
    int dg = valid ? deg[nc] : 0;
    int dgm = dg, o;
    o = __shfl_xor(dgm, 16, 64); dgm = dgm > o ? dgm : o;
    o = __shfl_xor(dgm, 32, 64); dgm = dgm > o ? dgm : o;
    uint2 su = *(const uint2*)(A + ((size_t)nc << 6) + 4 * m);
    float a0 = __uint_as_float(su.x << 16);
    float a1 = __uint_as_float(su.x & 0xffff0000u);
    float a2 = __uint_as_float(su.y << 16);
    float a3 = __uint_as_float(su.y & 0xffff0000u);
    int i = 0;
    for (; i + 8 <= dgm; i += 8) {
        uint2 u[8];
        #pragma unroll
        for (int j = 0; j < 8; ++j) {
            unsigned int s = (unsigned int)csr[base + i + j];
            if (s >= (unsigned int)N) s = 0;
            u[j] = *(const uint2*)(A + ((size_t)s << 6) + 4 * m);
        }
        #pragma unroll
        for (int j = 0; j < 8; ++j) {
            unsigned int ux = (i + j < dg) ? u[j].x : 0u;
            unsigned int uy = (i + j < dg) ? u[j].y : 0u;
            a0 += __uint_as_float(ux << 16);
            a1 += __uint_as_float(ux & 0xffff0000u);
            a2 += __uint_as_float(uy << 16);
            a3 += __uint_as_float(uy & 0xffff0000u);
        }
    }
    for (; i < dgm; ++i) {
        unsigned int s = (unsigned int)csr[base + i];
        if (s >= (unsigned int)N) s = 0;
        uint2 uu = *(const uint2*)(A + ((size_t)s << 6) + 4 * m);
        unsigned int ux = (i < dg) ? uu.x : 0u;
        unsigned int uy = (i < dg) ? uu.y : 0u;
        a0 += __uint_as_float(ux << 16);
        a1 += __uint_as_float(ux & 0xffff0000u);
        a2 += __uint_as_float(uy << 16);
        a3 += __uint_as_float(uy & 0xffff0000u);
    }
    float di = valid ? dinv[n] : 0.f;
    float4 bb = *(const float4*)(bias + 4 * m);
    float v0 = fmaxf(fmaf(di, a0, bb.x), 0.f);
    float v1 = fmaxf(fmaf(di, a1, bb.y), 0.f);
    float v2 = fmaxf(fmaf(di, a2, bb.z), 0.f);
    float v3 = fmaxf(fmaf(di, a3, bb.w), 0.f);
    if (valid) {
        uint2 pk;
        pk.x = (unsigned int)f2bf(v0) | ((unsigned int)f2bf(v1) << 16);
        pk.y = (unsigned int)f2bf(v2) | ((unsigned int)f2bf(v3) << 16);
        *(uint2*)&Ht[nl][4 * m] = pk;
    }
    __syncthreads();
    union { uint4 u; v8s s; } a0u, a1u;
    a0u.u = *(const uint4*)&Ht[m][q * 8];
    a1u.u = *(const uint4*)&Ht[m][32 + q * 8];
    v4f acc = {0.f, 0.f, 0.f, 0.f};
    acc = __builtin_amdgcn_mfma_f32_16x16x32_bf16(a0u.s, b0l, acc, 0, 0, 0);
    acc = __builtin_amdgcn_mfma_f32_16x16x32_bf16(a1u.s, b1l, acc, 0, 0, 0);
    acc = __builtin_amdgcn_mfma_f32_16x16x32_bf16(a0u.s, b0h, acc, 0, 0, 0);
    acc = __builtin_amdgcn_mfma_f32_16x16x32_bf16(a1u.s, b1h, acc, 0, 0, 0);
    #pragma unroll
    for (int r = 0; r < 4; ++r) {
        int node = n0 + q * 4 + r;
        if (node < N)
            A2[(size_t)node * 64 + cbase + m] = f2bf(acc[r] * dinv[node]);
    }
}

// ---- pull conv2 + mean-pool (4 ch/lane, LDS-transposed contiguous atomics, R12-proven) ----
__global__ void k_pull_pool(const unsigned short* __restrict__ A, const int* __restrict__ csr,
                            const int* __restrict__ offs, const int* __restrict__ deg,
                            const float* __restrict__ dinv, const float* __restrict__ bias,
                            const int* __restrict__ batch, float* __restrict__ pool, int N) {
    __shared__ float vt[4][4][64];
    int t = threadIdx.x;
    int lane = t & 63, wave = t >> 6;
    int q = lane >> 4, m = lane & 15;
    int n0 = blockIdx.x * 16;
    int nl = wave * 4 + q;
    int n = n0 + nl;
    bool valid = n < N;
    int nc = valid ? n : N - 1;
    int base = offs[nc];
    int dg = valid ? deg[nc] : 0;
    int dgm = dg, o;
    o = __shfl_xor(dgm, 16, 64); dgm = dgm > o ? dgm : o;
    o = __shfl_xor(dgm, 32, 64); dgm = dgm > o ? dgm : o;
    uint2 su = *(const uint2*)(A + ((size_t)nc << 6) + 4 * m);
    float a0 = __uint_as_float(su.x << 16);
    float a1 = __uint_as_float(su.x & 0xffff0000u);
    float a2 = __uint_as_float(su.y << 16);
    float a3 = __uint_as_float(su.y & 0xffff0000u);
    int i = 0;
    for (; i + 8 <= dgm; i += 8) {
        uint2 u[8];
        #pragma unroll
        for (int j = 0; j < 8; ++j) {
            unsigned int s = (unsigned int)csr[base + i + j];
            if (s >= (unsigned int)N) s = 0;
            u[j] = *(const uint2*)(A + ((size_t)s << 6) + 4 * m);
        }
        #pragma unroll
        for (int j = 0; j < 8; ++j) {
            unsigned int ux = (i + j < dg) ? u[j].x : 0u;
            unsigned int uy = (i + j < dg) ? u[j].y : 0u;
            a0 += __uint_as_float(ux << 16);
            a1 += __uint_as_float(ux & 0xffff0000u);
            a2 += __uint_as_float(uy << 16);
            a3 += __uint_as_float(uy & 0xffff0000u);
        }
    }
    for (; i < dgm; ++i) {
        unsigned int s = (unsigned int)csr[base + i];
        if (s >= (unsigned int)N) s = 0;
        uint2 uu = *(const uint2*)(A + ((size_t)s << 6) + 4 * m);
        unsigned int ux = (i < dg) ? uu.x : 0u;
        unsigned int uy = (i < dg) ? uu.y : 0u;
        a0 += __uint_as_float(ux << 16);
        a1 += __uint_as_float(ux & 0xffff0000u);
        a2 += __uint_as_float(uy << 16);
        a3 += __uint_as_float(uy & 0xffff0000u);
    }
    float di = valid ? dinv[n] : 0.f;
    float4 bb = *(const float4*)(bias + 4 * m);
    float4 vv;
    vv.x = fmaxf(fmaf(di, a0, bb.x), 0.f);
    vv.y = fmaxf(fmaf(di, a1, bb.y), 0.f);
    vv.z = fmaxf(fmaf(di, a2, bb.z), 0.f);
    vv.w = fmaxf(fmaf(di, a3, bb.w), 0.f);
    *(float4*)&vt[wave][q][4 * m] = vv;
    __syncthreads();
    int nw0 = n0 + wave * 4;
    #pragma unroll
    for (int r = 0; r < 4; ++r) {
        int nn = nw0 + r;
        if (nn < N) {
            float v = vt[wave][r][lane];
            atomicAdd(&pool[(size_t)batch[nn] * 64 + lane], v);
        }
    }
}

// per-graph head, 4 graphs per block; lin1W staged in LDS
__global__ void k_final4(const float* __restrict__ pool, const int* __restrict__ batch,
                         int N, int G,
                         const int* __restrict__ lig, const int* __restrict__ add,
                         const int* __restrict__ base, const int* __restrict__ aryl,
                         const float* __restrict__ e_lig, const float* __restrict__ e_add,
                         const float* __restrict__ e_base, const float* __restrict__ e_aryl,
                         const float* __restrict__ lin1W, const float* __restrict__ lin1b,
                         const float* __restrict__ lin2W, const float* __restrict__ lin2b,
                         float* __restrict__ out) {
    __shared__ float Wl[128 * 64];
    __shared__ float cat[4][128];
    int t = threadIdx.x;
    int c = t & 63, wv = t >> 6;
    for (int i = t; i < 128 * 64; i += 256) Wl[i] = lin1W[i];
    int g = blockIdx.x * 4 + wv;
    if (g < G) {
        int res = 0;
        if (c < 2) {
            int target = g + c;
            int lo = 0, hi = N;
            while (lo < hi) {
                int mid = (lo + hi) >> 1;
                if (batch[mid] < target) lo = mid + 1; else hi = mid;
            }
            res = lo;
        }
        int lo = __shfl(res, 0, 64), hi = __shfl(res, 1, 64);
        float invc = 1.0f / fmaxf((float)(hi - lo), 1.0f);
        cat[wv][c] = pool[(size_t)g * 64 + c] * invc;
        float ev;
        if (c < 16)      ev = e_lig[lig[g] * 16 + c];
        else if (c < 32) ev = e_add[add[g] * 16 + (c - 16)];
        else if (c < 48) ev = e_base[base[g] * 16 + (c - 32)];
        else             ev = e_aryl[aryl[g] * 16 + (c - 48)];
        cat[wv][64 + c] = ev;
    }
    __syncthreads();
    if (g < G) {
        float acc = lin1b[c];
        #pragma unroll
        for (int k = 0; k < 128; ++k) acc += cat[wv][k] * Wl[k * 64 + c];
        float p = fmaxf(acc, 0.f) * lin2W[c];
        #pragma unroll
        for (int off = 32; off > 0; off >>= 1) p += __shfl_down(p, off, 64);
        if (c == 0) out[g] = p + lin2b[0];
    }
}

extern "C" void kernel_launch(void* const* d_in, const int* in_sizes, int n_in,
                              void* d_out, int out_size, void* d_ws, size_t ws_size,
                              hipStream_t stream) {
    const float* x      = (const float*)d_in[0];
    const int*   ei     = (const int*)d_in[1];
    const int*   batch  = (const int*)d_in[2];
    const int*   lig    = (const int*)d_in[3];
    const int*   addi   = (const int*)d_in[4];
    const int*   basei  = (const int*)d_in[5];
    const int*   aryl   = (const int*)d_in[6];
    const float* e_lig  = (const float*)d_in[7];
    const float* e_add  = (const float*)d_in[8];
    const float* e_base = (const float*)d_in[9];
    const float* e_aryl = (const float*)d_in[10];
    const float* W1     = (const float*)d_in[11];
    const float* b1     = (const float*)d_in[12];
    const float* W2     = (const float*)d_in[13];
    const float* b2     = (const float*)d_in[14];
    const float* lin1W  = (const float*)d_in[15];
    const float* lin1b  = (const float*)d_in[16];
    const float* lin2W  = (const float*)d_in[17];
    const float* lin2b  = (const float*)d_in[18];
    float* out = (float*)d_out;

    const int N = in_sizes[0] / 6;
    const int E = in_sizes[1] / 2;
    const int G = in_sizes[3];
    const int* src = ei;
    const int* dst = ei + E;
    const int NBb = (N + BSZ - 1) / BSZ;   // 782 buckets

    // ---- workspace layout ----
    char* w = (char*)d_ws;
    size_t SA = (size_t)N * 64;
    unsigned short* A  = (unsigned short*)w;  w += SA * 2;  // Abar conv1 (bf16)
    unsigned short* A2 = (unsigned short*)w;  w += SA * 2;  // Abar conv2 (bf16)
    float* dinv = (float*)w;   w += (size_t)N * 4;
    int*   deg  = (int*)w;     w += (size_t)N * 4;
    int*   offs = (int*)w;     w += (size_t)N * 4;
    float* pool = (float*)w;   w += (size_t)G * 64 * 4;     // zeroed by k_partition
    int* bucket_cnt = (int*)w; w += (size_t)NBK * CNT_STRIDE * 4;  // padded; zeroed by memset
    unsigned int* buckets = (unsigned int*)w;  w += (size_t)NBb * CAP * 4;
    int* csr    = (int*)w;     w += (size_t)NBb * CAP * 4;
    w += 4096;   // slack: packed pulls read up to dgm past a node's csr end

    hipMemsetAsync(bucket_cnt, 0, (size_t)NBK * CNT_STRIDE * 4, stream);

    const int npart = (E + PCHUNK - 1) / PCHUNK;   // 391 blocks
    k_partition<<<npart, 256, 0, stream>>>(src, dst, E, bucket_cnt, buckets,
                                           pool, G * 64);
    k_bucket_csr_xw1<<<NBb, 256, 0, stream>>>(buckets, bucket_cnt,
                                              offs, deg, dinv, csr, x, W1, A, N);

    // conv1 pull (4ch/lane) + fused xw2 MFMA
    k_pull1_xw2<<<(N + 15) / 16, 256, 0, stream>>>(A, csr, offs, deg, dinv, b1, W2, A2, N);

    // conv2 + fused pooling (4ch/lane, LDS-transposed contiguous atomics)
    k_pull_pool<<<(N + 15) / 16, 256, 0, stream>>>(A2, csr, offs, deg, dinv, b2, batch, pool, N);

    // head (4 graphs per block)
    k_final4<<<(G + 3) / 4, 256, 0, stream>>>(pool, batch, N, G, lig, addi, basei, aryl,
                                              e_lig, e_add, e_base, e_aryl,
                                              lin1W, lin1b, lin2W, lin2b, out);
}

// Round 16
// 222.291 us; speedup vs baseline: 3.1764x; 1.1102x over previous
//
#include <hip/hip_runtime.h>
#include <hip/hip_bf16.h>

#define PCHUNK 4096
#define NBK 1024      // hist width (padded); used buckets = ceil(100000/128) = 782
#define BSZ 128       // nodes per bucket
#define CAP 2560      // per-bucket edge capacity (mean 2046, +11 sigma)
#define CNT_STRIDE 16 // bucket_cnt padded: one 64B cacheline per bucket

__device__ inline float bf2f(unsigned int u16) { return __uint_as_float(u16 << 16); }
__device__ inline unsigned short f2bf(float f) {
    __hip_bfloat16 b = __float2bfloat16(f);
    return *(unsigned short*)&b;
}

typedef __attribute__((ext_vector_type(8))) short v8s;
typedef __attribute__((ext_vector_type(4))) float v4f;

// ---- phase 1: partition edges into 128-node dst-buckets; also zeroes pool (R15-proven) ----
__global__ void k_partition(const int* __restrict__ src, const int* __restrict__ dst, int E,
                            int* __restrict__ bucket_cnt, unsigned int* __restrict__ buckets,
                            float* __restrict__ zero_base, int zero_count) {
    __shared__ int hist[NBK];
    __shared__ int shift[NBK];
    __shared__ int cursor[NBK];
    __shared__ unsigned int staged_e[PCHUNK];
    __shared__ unsigned short staged_b[PCHUNK];
    __shared__ int wtot[4];
    int t = threadIdx.x;
    int lane = t & 63, wave = t >> 6;
    int base = blockIdx.x * PCHUNK;
    for (int i = blockIdx.x * 256 + t; i < zero_count; i += gridDim.x * 256)
        zero_base[i] = 0.f;
    for (int i = t; i < NBK; i += 256) hist[i] = 0;
    __syncthreads();
    int nE = E - base; if (nE > PCHUNK) nE = PCHUNK;
    for (int i = t; i < nE; i += 256) atomicAdd(&hist[dst[base + i] >> 7], 1);
    __syncthreads();
    int h0 = hist[4 * t], h1 = hist[4 * t + 1], h2 = hist[4 * t + 2], h3 = hist[4 * t + 3];
    int p1 = h0 + h1, p2 = p1 + h2, s = p2 + h3;
    int si = s;
    #pragma unroll
    for (int off = 1; off < 64; off <<= 1) {
        int u = __shfl_up(si, off, 64);
        if (lane >= off) si += u;
    }
    if (lane == 63) wtot[wave] = si;
    __syncthreads();
    int woff = 0;
    #pragma unroll
    for (int w2 = 0; w2 < 4; ++w2) woff += (w2 < wave) ? wtot[w2] : 0;
    int ebase = woff + si - s;
    int ex[4] = {ebase, ebase + h0, ebase + p1, ebase + p2};
    int cn[4] = {h0, h1, h2, h3};
    #pragma unroll
    for (int j = 0; j < 4; ++j) {
        int bidx = 4 * t + j;
        cursor[bidx] = ex[j];
        if (cn[j] > 0) {
            int g = atomicAdd(&bucket_cnt[bidx * CNT_STRIDE], cn[j]);
            shift[bidx] = g - ex[j];
        }
    }
    __syncthreads();
    for (int i = t; i < nE; i += 256) {
        int d = dst[base + i];
        int b = d >> 7;
        int r = atomicAdd(&cursor[b], 1);
        staged_e[r] = (unsigned int)src[base + i] | ((unsigned int)(d & (BSZ - 1)) << 24);
        staged_b[r] = (unsigned short)b;
    }
    __syncthreads();
    for (int i = t; i < nE; i += 256) {
        int b = staged_b[i];
        buckets[(size_t)b * CAP + shift[b] + i] = staged_e[i];
    }
}

// ---- phase 2: per-bucket CSR build + xd = fp32 (x * dinv), padded to 8 floats/node ----
__global__ void k_bucket_csr_xd(const unsigned int* __restrict__ buckets,
                                const int* __restrict__ bucket_cnt,
                                int* __restrict__ offs, int* __restrict__ deg,
                                float* __restrict__ dinv, int* __restrict__ csr,
                                const float* __restrict__ x,
                                float* __restrict__ xd, int N) {
    __shared__ int dl[BSZ], cur[BSZ];
    __shared__ float dis[BSZ];
    __shared__ float xs[BSZ * 6];
    __shared__ int w0tot;
    int b = blockIdx.x, t = threadIdx.x;
    int nb0 = b * BSZ;
    for (int i = t; i < BSZ * 6; i += 256) {
        int node = nb0 + i / 6;
        xs[i] = (node < N) ? x[(size_t)nb0 * 6 + i] : 0.f;
    }
    if (t < BSZ) dl[t] = 0;
    __syncthreads();
    int cnt = bucket_cnt[b * CNT_STRIDE];
    if (cnt > CAP) cnt = CAP;
    const unsigned int* bp = buckets + (size_t)b * CAP;
    for (int i = t; i < cnt; i += 256) atomicAdd(&dl[bp[i] >> 24], 1);
    __syncthreads();
    int lane = t & 63, wave = t >> 6;
    int v = (t < BSZ) ? dl[t] : 0;
    int si = v;
    #pragma unroll
    for (int off = 1; off < 64; off <<= 1) {
        int u = __shfl_up(si, off, 64);
        if (lane >= off) si += u;
    }
    if (t == 63) w0tot = si;
    __syncthreads();
    int ex = si - v + ((wave == 1) ? w0tot : 0);
    if (t < BSZ) {
        cur[t] = ex;
        float di = rsqrtf((float)v + 1.0f);
        dis[t] = di;
        int n = nb0 + t;
        if (n < N) { offs[n] = b * CAP + ex; deg[n] = v; dinv[n] = di; }
    }
    __syncthreads();
    int* cg = csr + (size_t)b * CAP;
    for (int i = t; i < cnt; i += 256) {
        unsigned int e = bp[i];
        int r = atomicAdd(&cur[e >> 24], 1);
        cg[r] = (int)(e & 0x00FFFFFFu);
    }
    // xd[node][8] = {x*dinv (6), 0, 0}; 128 nodes * 8 floats = 1024, 4 per thread
    #pragma unroll
    for (int j = 0; j < 4; ++j) {
        int idx = t + j * 256;
        int nl = idx >> 3, c = idx & 7;
        int node = nb0 + nl;
        if (node < N)
            xd[((size_t)node << 3) + c] = (c < 6) ? xs[nl * 6 + c] * dis[nl] : 0.f;
    }
}

// ---- conv1 pull in 6-dim input space + W1 matvec + fused xw2 MFMA.
//      Block = 32 nodes (two 16-node MFMA tiles). Wave pulls 8 nodes
//      (oct = node, lane&7 = channel of fp32 xd row, 32 B/row). ----
__global__ void k_pull1_xw2(const float* __restrict__ xd, const int* __restrict__ csr,
                            const int* __restrict__ offs, const int* __restrict__ deg,
                            const float* __restrict__ dinv,
                            const float* __restrict__ W1, const float* __restrict__ b1,
                            const float* __restrict__ W2, unsigned short* __restrict__ A2,
                            int N) {
    __shared__ float agg6[32][8];
    __shared__ unsigned short Ht[32][72];
    __shared__ float W1s[6 * 64];
    int t = threadIdx.x;
    int lane = t & 63, wave = t >> 6;
    int q = lane >> 4, m16 = lane & 15;
    int cbase = wave * 16;
    for (int i = t; i < 6 * 64; i += 256) W1s[i] = W1[i];
    // W2 B-fragments (hi/lo split) — identical mapping to the verified kernel
    v8s b0h, b0l, b1h, b1l;
    #pragma unroll
    for (int j = 0; j < 8; ++j) {
        float w0 = W2[(q * 8 + j) * 64 + cbase + m16];
        unsigned short h0 = f2bf(w0);
        b0h[j] = (short)h0;
        b0l[j] = (short)f2bf(w0 - bf2f(h0));
        float w1 = W2[(32 + q * 8 + j) * 64 + cbase + m16];
        unsigned short h1 = f2bf(w1);
        b1h[j] = (short)h1;
        b1l[j] = (short)f2bf(w1 - bf2f(h1));
    }
    int n0 = blockIdx.x * 32;
    // ---- pull: 8 nodes per wave (oct = lane>>3), channel m = lane&7 ----
    int oct = lane >> 3, m = lane & 7;
    int nl = wave * 8 + oct;
    int n = n0 + nl;
    bool valid = n < N;
    int nc = valid ? n : N - 1;
    int base = offs[nc];
    int dg = valid ? deg[nc] : 0;
    int dgm = dg, o;
    o = __shfl_xor(dgm, 8, 64);  dgm = dgm > o ? dgm : o;
    o = __shfl_xor(dgm, 16, 64); dgm = dgm > o ? dgm : o;
    o = __shfl_xor(dgm, 32, 64); dgm = dgm > o ? dgm : o;
    float a = xd[((size_t)nc << 3) + m];
    int i = 0;
    for (; i + 8 <= dgm; i += 8) {
        float u[8];
        #pragma unroll
        for (int j = 0; j < 8; ++j) {
            unsigned int s = (unsigned int)csr[base + i + j];
            if (s >= (unsigned int)N) s = 0;   // tail/poison clamp
            u[j] = xd[((size_t)s << 3) + m];
        }
        #pragma unroll
        for (int j = 0; j < 8; ++j)
            a += (i + j < dg) ? u[j] : 0.f;
    }
    for (; i < dgm; ++i) {
        unsigned int s = (unsigned int)csr[base + i];
        if (s >= (unsigned int)N) s = 0;
        float u = xd[((size_t)s << 3) + m];
        a += (i < dg) ? u : 0.f;
    }
    agg6[nl][m] = (valid ? dinv[n] : 0.f) * a;
    __syncthreads();
    // ---- h1 = relu(agg6 @ W1 + b1) -> Ht (bf16), 32 nodes x 64 ch ----
    float bl = b1[lane];
    #pragma unroll
    for (int r = 0; r < 8; ++r) {
        int node_l = wave * 8 + r;
        float acc = bl;
        #pragma unroll
        for (int k = 0; k < 6; ++k) acc += agg6[node_l][k] * W1s[k * 64 + lane];
        Ht[node_l][lane] = f2bf(fmaxf(acc, 0.f));
    }
    __syncthreads();
    // ---- MFMA phase: two 16-node tiles, each wave does cbase for both ----
    #pragma unroll
    for (int tile = 0; tile < 2; ++tile) {
        int row = tile * 16 + m16;
        union { uint4 u; v8s s; } a0u, a1u;
        a0u.u = *(const uint4*)&Ht[row][q * 8];
        a1u.u = *(const uint4*)&Ht[row][32 + q * 8];
        v4f acc = {0.f, 0.f, 0.f, 0.f};
        acc = __builtin_amdgcn_mfma_f32_16x16x32_bf16(a0u.s, b0l, acc, 0, 0, 0);
        acc = __builtin_amdgcn_mfma_f32_16x16x32_bf16(a1u.s, b1l, acc, 0, 0, 0);
        acc = __builtin_amdgcn_mfma_f32_16x16x32_bf16(a0u.s, b0h, acc, 0, 0, 0);
        acc = __builtin_amdgcn_mfma_f32_16x16x32_bf16(a1u.s, b1h, acc, 0, 0, 0);
        #pragma unroll
        for (int r = 0; r < 4; ++r) {
            int node = n0 + tile * 16 + q * 4 + r;   // C/D: col=lane&15, row=(lane>>4)*4+r
            if (node < N)
                A2[(size_t)node * 64 + cbase + m16] = f2bf(acc[r] * dinv[node]);
        }
    }
}

// ---- pull conv2 + mean-pool (4 ch/lane, LDS-transposed contiguous atomics, R12-proven) ----
__global__ void k_pull_pool(const unsigned short* __restrict__ A, const int* __restrict__ csr,
                            const int* __restrict__ offs, const int* __restrict__ deg,
                            const float* __restrict__ dinv, const float* __restrict__ bias,
                            const int* __restrict__ batch, float* __restrict__ pool, int N) {
    __shared__ float vt[4][4][64];
    int t = threadIdx.x;
    int lane = t & 63, wave = t >> 6;
    int q = lane >> 4, m = lane & 15;
    int n0 = blockIdx.x * 16;
    int nl = wave * 4 + q;
    int n = n0 + nl;
    bool valid = n < N;
    int nc = valid ? n : N - 1;
    int base = offs[nc];
    int dg = valid ? deg[nc] : 0;
    int dgm = dg, o;
    o = __shfl_xor(dgm, 16, 64); dgm = dgm > o ? dgm : o;
    o = __shfl_xor(dgm, 32, 64); dgm = dgm > o ? dgm : o;
    uint2 su = *(const uint2*)(A + ((size_t)nc << 6) + 4 * m);
    float a0 = __uint_as_float(su.x << 16);
    float a1 = __uint_as_float(su.x & 0xffff0000u);
    float a2 = __uint_as_float(su.y << 16);
    float a3 = __uint_as_float(su.y & 0xffff0000u);
    int i = 0;
    for (; i + 8 <= dgm; i += 8) {
        uint2 u[8];
        #pragma unroll
        for (int j = 0; j < 8; ++j) {
            unsigned int s = (unsigned int)csr[base + i + j];
            if (s >= (unsigned int)N) s = 0;
            u[j] = *(const uint2*)(A + ((size_t)s << 6) + 4 * m);
        }
        #pragma unroll
        for (int j = 0; j < 8; ++j) {
            unsigned int ux = (i + j < dg) ? u[j].x : 0u;
            unsigned int uy = (i + j < dg) ? u[j].y : 0u;
            a0 += __uint_as_float(ux << 16);
            a1 += __uint_as_float(ux & 0xffff0000u);
            a2 += __uint_as_float(uy << 16);
            a3 += __uint_as_float(uy & 0xffff0000u);
        }
    }
    for (; i < dgm; ++i) {
        unsigned int s = (unsigned int)csr[base + i];
        if (s >= (unsigned int)N) s = 0;
        uint2 uu = *(const uint2*)(A + ((size_t)s << 6) + 4 * m);
        unsigned int ux = (i < dg) ? uu.x : 0u;
        unsigned int uy = (i < dg) ? uu.y : 0u;
        a0 += __uint_as_float(ux << 16);
        a1 += __uint_as_float(ux & 0xffff0000u);
        a2 += __uint_as_float(uy << 16);
        a3 += __uint_as_float(uy & 0xffff0000u);
    }
    float di = valid ? dinv[n] : 0.f;
    float4 bb = *(const float4*)(bias + 4 * m);
    float4 vv;
    vv.x = fmaxf(fmaf(di, a0, bb.x), 0.f);
    vv.y = fmaxf(fmaf(di, a1, bb.y), 0.f);
    vv.z = fmaxf(fmaf(di, a2, bb.z), 0.f);
    vv.w = fmaxf(fmaf(di, a3, bb.w), 0.f);
    *(float4*)&vt[wave][q][4 * m] = vv;
    __syncthreads();
    int nw0 = n0 + wave * 4;
    #pragma unroll
    for (int r = 0; r < 4; ++r) {
        int nn = nw0 + r;
        if (nn < N) {
            float v = vt[wave][r][lane];
            atomicAdd(&pool[(size_t)batch[nn] * 64 + lane], v);
        }
    }
}

// per-graph head, 4 graphs per block; lin1W staged in LDS
__global__ void k_final4(const float* __restrict__ pool, const int* __restrict__ batch,
                         int N, int G,
                         const int* __restrict__ lig, const int* __restrict__ add,
                         const int* __restrict__ base, const int* __restrict__ aryl,
                         const float* __restrict__ e_lig, const float* __restrict__ e_add,
                         const float* __restrict__ e_base, const float* __restrict__ e_aryl,
                         const float* __restrict__ lin1W, const float* __restrict__ lin1b,
                         const float* __restrict__ lin2W, const float* __restrict__ lin2b,
                         float* __restrict__ out) {
    __shared__ float Wl[128 * 64];
    __shared__ float cat[4][128];
    int t = threadIdx.x;
    int c = t & 63, wv = t >> 6;
    for (int i = t; i < 128 * 64; i += 256) Wl[i] = lin1W[i];
    int g = blockIdx.x * 4 + wv;
    if (g < G) {
        int res = 0;
        if (c < 2) {
            int target = g + c;
            int lo = 0, hi = N;
            while (lo < hi) {
                int mid = (lo + hi) >> 1;
                if (batch[mid] < target) lo = mid + 1; else hi = mid;
            }
            res = lo;
        }
        int lo = __shfl(res, 0, 64), hi = __shfl(res, 1, 64);
        float invc = 1.0f / fmaxf((float)(hi - lo), 1.0f);
        cat[wv][c] = pool[(size_t)g * 64 + c] * invc;
        float ev;
        if (c < 16)      ev = e_lig[lig[g] * 16 + c];
        else if (c < 32) ev = e_add[add[g] * 16 + (c - 16)];
        else if (c < 48) ev = e_base[base[g] * 16 + (c - 32)];
        else             ev = e_aryl[aryl[g] * 16 + (c - 48)];
        cat[wv][64 + c] = ev;
    }
    __syncthreads();
    if (g < G) {
        float acc = lin1b[c];
        #pragma unroll
        for (int k = 0; k < 128; ++k) acc += cat[wv][k] * Wl[k * 64 + c];
        float p = fmaxf(acc, 0.f) * lin2W[c];
        #pragma unroll
        for (int off = 32; off > 0; off >>= 1) p += __shfl_down(p, off, 64);
        if (c == 0) out[g] = p + lin2b[0];
    }
}

extern "C" void kernel_launch(void* const* d_in, const int* in_sizes, int n_in,
                              void* d_out, int out_size, void* d_ws, size_t ws_size,
                              hipStream_t stream) {
    const float* x      = (const float*)d_in[0];
    const int*   ei     = (const int*)d_in[1];
    const int*   batch  = (const int*)d_in[2];
    const int*   lig    = (const int*)d_in[3];
    const int*   addi   = (const int*)d_in[4];
    const int*   basei  = (const int*)d_in[5];
    const int*   aryl   = (const int*)d_in[6];
    const float* e_lig  = (const float*)d_in[7];
    const float* e_add  = (const float*)d_in[8];
    const float* e_base = (const float*)d_in[9];
    const float* e_aryl = (const float*)d_in[10];
    const float* W1     = (const float*)d_in[11];
    const float* b1     = (const float*)d_in[12];
    const float* W2     = (const float*)d_in[13];
    const float* b2     = (const float*)d_in[14];
    const float* lin1W  = (const float*)d_in[15];
    const float* lin1b  = (const float*)d_in[16];
    const float* lin2W  = (const float*)d_in[17];
    const float* lin2b  = (const float*)d_in[18];
    float* out = (float*)d_out;

    const int N = in_sizes[0] / 6;
    const int E = in_sizes[1] / 2;
    const int G = in_sizes[3];
    const int* src = ei;
    const int* dst = ei + E;
    const int NBb = (N + BSZ - 1) / BSZ;   // 782 buckets

    // ---- workspace layout ----
    char* w = (char*)d_ws;
    size_t SA = (size_t)N * 64;
    float* xd = (float*)w;     w += (size_t)N * 8 * 4;      // x*dinv, fp32, 8/node
    unsigned short* A2 = (unsigned short*)w;  w += SA * 2;  // Abar conv2 (bf16)
    float* dinv = (float*)w;   w += (size_t)N * 4;
    int*   deg  = (int*)w;     w += (size_t)N * 4;
    int*   offs = (int*)w;     w += (size_t)N * 4;
    float* pool = (float*)w;   w += (size_t)G * 64 * 4;     // zeroed by k_partition
    int* bucket_cnt = (int*)w; w += (size_t)NBK * CNT_STRIDE * 4;  // padded; zeroed by memset
    unsigned int* buckets = (unsigned int*)w;  w += (size_t)NBb * CAP * 4;
    int* csr    = (int*)w;     w += (size_t)NBb * CAP * 4;
    w += 4096;   // slack: packed pulls read up to dgm past a node's csr end

    hipMemsetAsync(bucket_cnt, 0, (size_t)NBK * CNT_STRIDE * 4, stream);

    const int npart = (E + PCHUNK - 1) / PCHUNK;   // 391 blocks
    k_partition<<<npart, 256, 0, stream>>>(src, dst, E, bucket_cnt, buckets,
                                           pool, G * 64);
    k_bucket_csr_xd<<<NBb, 256, 0, stream>>>(buckets, bucket_cnt,
                                             offs, deg, dinv, csr, x, xd, N);

    // conv1 pull in 6-dim space + W1 + fused xw2 MFMA (32 nodes/block)
    k_pull1_xw2<<<(N + 31) / 32, 256, 0, stream>>>(xd, csr, offs, deg, dinv,
                                                   W1, b1, W2, A2, N);

    // conv2 + fused pooling (4ch/lane, LDS-transposed contiguous atomics)
    k_pull_pool<<<(N + 15) / 16, 256, 0, stream>>>(A2, csr, offs, deg, dinv, b2, batch, pool, N);

    // head (4 graphs per block)
    k_final4<<<(G + 3) / 4, 256, 0, stream>>>(pool, batch, N, G, lig, addi, basei, aryl,
                                              e_lig, e_add, e_base, e_aryl,
                                              lin1W, lin1b, lin2W, lin2b, out);
}